// Round 10
// baseline (258.535 us; speedup 1.0000x reference)
//
#include <hip/hip_runtime.h>

#define NB 1024
#define NS 1024
#define NT 32
#define L2E 1.44269504088896340736f
#define LN2 0.69314718055994530942f

typedef short        bfrag  __attribute__((ext_vector_type(8)));   // 8 bf16 (4 VGPR)
typedef float        cfrag  __attribute__((ext_vector_type(16)));  // 16 f32 acc
typedef __bf16       bf16x2 __attribute__((ext_vector_type(2)));
typedef float        f32x8  __attribute__((ext_vector_type(8)));
typedef float        f32x4  __attribute__((ext_vector_type(4)));
typedef float        f32x2  __attribute__((ext_vector_type(2)));
typedef unsigned int u32;
typedef unsigned int u32x4  __attribute__((ext_vector_type(4)));

__device__ __forceinline__ float fexp2(float x){ return __builtin_amdgcn_exp2f(x); }
__device__ __forceinline__ float flog2(float x){ return __builtin_amdgcn_logf(x); }

// RNE pack (prologue only)
__device__ __forceinline__ u32 pkbf_rne(float a, float b){
    f32x2 t; t.x = a; t.y = b;
    return __builtin_bit_cast(u32, __builtin_convertvector(t, bf16x2));
}
// truncation pack: single v_perm_b32. low16 = bf16_trunc(a), high16 = bf16_trunc(b).
__device__ __forceinline__ u32 pkbf_t(float a, float b){
    return __builtin_amdgcn_perm(__builtin_bit_cast(u32, b),
                                 __builtin_bit_cast(u32, a), 0x07060302u);
}
// wave-uniform power-of-2 exponent extract (clamped)
__device__ __forceinline__ int exref(float ref){
    u32 xb = __builtin_bit_cast(u32, ref);
    u32 xf = __builtin_amdgcn_readfirstlane(xb);
    int ex = (int)((xf >> 23) & 0xFFu) - 127;
    return ex < -120 ? -120 : (ex > 120 ? 120 : ex);
}

// row-space involution applied implicitly by packing C/D straight into B regs:
// swaps row blocks [4..7]<->[8..11] and [20..23]<->[24..27].
__device__ __forceinline__ int rho(int k){
    int bb = (k >> 2) & 3;
    return (bb == 1 || bb == 2) ? (k ^ 12) : k;
}

template<int N> struct ic { static constexpr int value = N; };
union accu { cfrag c; f32x2 p[8]; };
union e8u  { f32x8 v; f32x2 p[4]; };

#define MFMA2(Au, Bu, C) __builtin_amdgcn_mfma_f32_32x32x16_bf16( \
    __builtin_bit_cast(bfrag, Au), __builtin_bit_cast(bfrag, Bu), (C), 0, 0, 0)

// ---------------- Phase 1: per-(batch,chunk) transfer matrix + gold ----------
// LDS-FREE loop. r9 showed the kernel invariant to occupancy (56/34/55%), ILP
// (dual-chain), and VALU diet — the one constant was the per-step LDS round trip
// (4 broadcast ds_read_b128 + lgkmcnt on the critical path, ~1KB/step/wave of
// LDS return traffic ~= 54-81us of pipe demand). This version folds the diagonal
// into the A-operand instead: D_t*(E^T*M) = (D_t*E^T)*M, and the A-frag row
// index is LANE-UNIFORM (lane m holds row m), so d_t[m]=exp2(e_t[m]) is a
// lane-local scalar: per step scale the f32 E copy (8 pk_mul) and pack (8 perm).
// No __shared__, no commit phase, no lgkmcnt in the loop. Group renorm folds
// into s at each group's step 0 (s = exp2(L2E*e - exf)) exactly as before.
__global__ __launch_bounds__(128, 6) void crf_chunk(
    const float* __restrict__ logits, const float* __restrict__ trans,
    const int* __restrict__ tags, const int* __restrict__ lens,
    u32* __restrict__ wmat, float* __restrict__ woff,
    float* __restrict__ gpart, float* __restrict__ outz)
{
    const int tid = threadIdx.x;
    const int wv  = tid >> 6, lt = tid & 63;
    const int m   = lt & 31,  h  = lt >> 5;
    const int bc  = blockIdx.x * 2 + wv;
    const int b   = bc >> 3,  c  = bc & 7;

    if (blockIdx.x == 0 && tid == 0) *outz = 0.0f;    // replaces memset dispatch

    const float* base = logits + (size_t)b * NS * NT;
    const int    len  = lens[b];
    const int    tb   = b * NS;

    // E in f32, rho-compensated k index: E'[m][k] = exp(trans[rho(k)][m])
    e8u Et0, Et1;
    #pragma unroll
    for (int j = 0; j < 8; j++){
        Et0.v[j] = fexp2(L2E * trans[rho(     8*h + j)*NT + m]);
        Et1.v[j] = fexp2(L2E * trans[rho(16 + 8*h + j)*NT + m]);
    }

    // B = rho-permuted identity (packed bf16): slot k holds row rho(k)
    u32x4 B0v, B1v;
    #pragma unroll
    for (int d = 0; d < 4; d++){
        int k0 = 8*h + 2*d;      u32 v = 0;
        if (rho(k0)     == m) v |= 0x3F80u;
        if (rho(k0 + 1) == m) v |= 0x3F800000u;
        B0v[d] = v;
        int k1 = 16 + 8*h + 2*d; v = 0;
        if (rho(k1)     == m) v |= 0x3F80u;
        if (rho(k1 + 1) == m) v |= 0x3F800000u;
        B1v[d] = v;
    }

    cfrag zacc;
    #pragma unroll
    for (int q = 0; q < 16; q++) zacc[q] = 0.0f;

    int   offi = 0;        // accumulated log2 scale (integer, wave-uniform)
    float exf  = 0.0f;     // deferred scale folded into next group's step-0 s
    const int tbeg = c*128 + 1;

    float eA[8], eB[8];

    // 8 emission loads per group per lane (lane's own row m; both halves load
    // the same 128B line per step -> coalesced, no extra cache traffic)
    auto issue = [&](float (&e)[8], int k){
        const int t0 = tbeg + k*8;
        #pragma unroll
        for (int i = 0; i < 8; i++){
            int t = t0 + i; t = t > (NS-1) ? (NS-1) : t;   // clamp c==7 tail
            e[i] = base[t*NT + m];
        }
    };

    auto procN = [&](float (&e)[8], bool defer, auto nstc){
        constexpr int NST = decltype(nstc)::value;
        #pragma unroll
        for (int i = 0; i < NST; i++){
            // lane-local diagonal scale (group-start folds the deferred renorm)
            float s = (i == 0) ? fexp2(fmaf(L2E, e[0], -exf))
                               : fexp2(L2E * e[i]);
            f32x2 s2; s2.x = s; s2.y = s;

            // A_t = pack(E .* s): 8 pk_mul + 8 v_perm, all lane-local
            u32x4 A0p, A1p;
            {
                f32x2 r0 = Et0.p[0]*s2, r1 = Et0.p[1]*s2;
                f32x2 r2 = Et0.p[2]*s2, r3 = Et0.p[3]*s2;
                A0p[0] = pkbf_t(r0.x, r0.y); A0p[1] = pkbf_t(r1.x, r1.y);
                A0p[2] = pkbf_t(r2.x, r2.y); A0p[3] = pkbf_t(r3.x, r3.y);
                f32x2 q0 = Et1.p[0]*s2, q1 = Et1.p[1]*s2;
                f32x2 q2 = Et1.p[2]*s2, q3 = Et1.p[3]*s2;
                A1p[0] = pkbf_t(q0.x, q0.y); A1p[1] = pkbf_t(q1.x, q1.y);
                A1p[2] = pkbf_t(q2.x, q2.y); A1p[3] = pkbf_t(q3.x, q3.y);
            }

            accu acc;
            acc.c = MFMA2(A0p, B0v, zacc);
            acc.c = MFMA2(A1p, B1v, acc.c);

            // group-end renorm: record only; applied via next group's s (free)
            if (i == 7 && defer){
                int ex = exref(fmaxf(acc.c[0], acc.c[8]));
                offi += ex;
                exf = (float)ex;
            }

            // pack C/D straight into B regs (lane-local; applies rho implicitly)
            B0v[0] = pkbf_t(acc.c[0],  acc.c[1]);  B0v[1] = pkbf_t(acc.c[2],  acc.c[3]);
            B0v[2] = pkbf_t(acc.c[4],  acc.c[5]);  B0v[3] = pkbf_t(acc.c[6],  acc.c[7]);
            B1v[0] = pkbf_t(acc.c[8],  acc.c[9]);  B1v[1] = pkbf_t(acc.c[10], acc.c[11]);
            B1v[2] = pkbf_t(acc.c[12], acc.c[13]); B1v[3] = pkbf_t(acc.c[14], acc.c[15]);
        }
    };

    issue(eA, 0);
    #pragma unroll 1
    for (int k = 0; k < 14; k += 2){
        issue(eB, k + 1);
        procN(eA, true, ic<8>{});
        issue(eA, k + 2);
        procN(eB, true, ic<8>{});
    }
    issue(eB, 15);
    procN(eA, true, ic<8>{});                 // group 14
    if (c != 7) procN(eB, false, ic<8>{});    // group 15 (wave-uniform branch)
    else        procN(eB, false, ic<7>{});    // chunk 7 has 127 steps

    // ---- store frag contiguously per lane: wmat[bc*512 + lt*8 + d] (2x dwordx4)
    {
        u32* wp = wmat + (size_t)bc * 512 + (size_t)lt * 8;
        *(u32x4*)(wp)     = B0v;
        *(u32x4*)(wp + 4) = B1v;
    }
    if (lt == 0) woff[bc] = (float)offi;

    // ---- gold for this chunk's 128 positions (t = tbeg..tbeg+127), 2/lane.
    {
        const int t1 = tbeg + 2*lt;
        const int t2 = t1 + 1;
        const int i2 = t2 > (NS-1) ? (NS-1) : t2;   // c==7,lt==63: t2==1024
        const int g0 = tags[tb + t1 - 1];
        const int g1 = tags[tb + t1];
        const int g2 = tags[tb + i2];
        float gg = 0.0f;
        if (t1 < len) gg += base[t1*NT + g1] + trans[g0*NT + g1];
        if (t2 < len) gg += base[t2*NT + g2] + trans[g1*NT + g2];
        #pragma unroll
        for (int d = 1; d < 64; d <<= 1) gg += __shfl_xor(gg, d, 64);
        if (lt == 0){
            if (c == 0) gg += base[tags[tb]];        // t=0 emission
            gpart[bc] = gg;                          // plain store, no atomic
        }
    }
}

// ---------------- Phase 2: per-batch MFMA matrix-chain combine ----------------
// UNCHANGED from round 6 (verified).
__global__ __launch_bounds__(256) void crf_combine(
    const float* __restrict__ logits,
    const u32* __restrict__ wmat, const float* __restrict__ woff,
    const float* __restrict__ gpart, float* __restrict__ out)
{
    const int tid = threadIdx.x;
    const int wv  = tid >> 6, lt = tid & 63;
    const int m   = lt & 31,  h  = lt >> 5;
    const int b   = blockIdx.x * 4 + wv;
    const float* base = logits + (size_t)b * NS * NT;

    uint4 mf[16];
    const u32* wb = wmat + (size_t)b * 8 * 512 + (size_t)lt * 8;
    #pragma unroll
    for (int j = 0; j < 8; j++){
        mf[2*j]     = *(const uint4*)(wb + j*512);
        mf[2*j + 1] = *(const uint4*)(wb + j*512 + 4);
    }

    float4 gp0 = ((const float4*)(gpart + b*8))[0];
    float4 gp1 = ((const float4*)(gpart + b*8))[1];
    const float gold = (gp0.x + gp0.y) + (gp0.z + gp0.w)
                     + (gp1.x + gp1.y) + (gp1.z + gp1.w);

    float voff = 0.0f;
    #pragma unroll
    for (int cc = 0; cc < 8; cc++) voff += woff[b*8 + cc];

    u32x4 S0, S1;
    #pragma unroll
    for (int d = 0; d < 4; d++){
        int k0 = 8*h + 2*d;      u32 v = 0;
        if (rho(k0)     == m) v |= 0x3F80u;
        if (rho(k0 + 1) == m) v |= 0x3F800000u;
        S0[d] = v;
        int k1 = 16 + 8*h + 2*d; v = 0;
        if (rho(k1)     == m) v |= 0x3F80u;
        if (rho(k1 + 1) == m) v |= 0x3F800000u;
        S1[d] = v;
    }

    cfrag zacc;
    #pragma unroll
    for (int q = 0; q < 16; q++) zacc[q] = 0.0f;

    #pragma unroll
    for (int j = 7; j >= 0; j--){
        accu acc;
        acc.c = MFMA2(mf[2*j],     S0, zacc);
        acc.c = MFMA2(mf[2*j + 1], S1, acc.c);

        float mx = acc.c[0];
        #pragma unroll
        for (int q = 1; q < 16; q++) mx = fmaxf(mx, acc.c[q]);
        #pragma unroll
        for (int d = 1; d < 64; d <<= 1) mx = fmaxf(mx, __shfl_xor(mx, d, 64));
        int ex = exref(mx);
        float sc = __builtin_bit_cast(float, (u32)(127 - ex) << 23);
        #pragma unroll
        for (int q = 0; q < 16; q++) acc.c[q] *= sc;
        voff += (float)ex;

        S0[0] = pkbf_t(acc.c[0],  acc.c[1]);  S0[1] = pkbf_t(acc.c[2],  acc.c[3]);
        S0[2] = pkbf_t(acc.c[4],  acc.c[5]);  S0[3] = pkbf_t(acc.c[6],  acc.c[7]);
        S1[0] = pkbf_t(acc.c[8],  acc.c[9]);  S1[1] = pkbf_t(acc.c[10], acc.c[11]);
        S1[2] = pkbf_t(acc.c[12], acc.c[13]); S1[3] = pkbf_t(acc.c[14], acc.c[15]);
    }

    u32x4 V0, V1;
    #pragma unroll
    for (int d = 0; d < 4; d++){
        int k0 = 8*h + 2*d;
        V0[d] = pkbf_rne(fexp2(L2E * base[rho(k0)]), fexp2(L2E * base[rho(k0+1)]));
        int k1 = 16 + 8*h + 2*d;
        V1[d] = pkbf_rne(fexp2(L2E * base[rho(k1)]), fexp2(L2E * base[rho(k1+1)]));
    }

    accu fin;
    fin.c = MFMA2(S0, V0, zacc);
    fin.c = MFMA2(S1, V1, fin.c);

    float s = 0.0f;
    #pragma unroll
    for (int q = 0; q < 16; q++) s += fin.c[q];
    s += __shfl_xor(s, 32, 64);

    if (lt == 0){
        float logz = LN2 * (voff + flog2(s));
        atomicAdd(out, (logz - gold) * (1.0f / (float)NB));
    }
}

extern "C" void kernel_launch(void* const* d_in, const int* in_sizes, int n_in,
                              void* d_out, int out_size, void* d_ws, size_t ws_size,
                              hipStream_t stream) {
    const float* logits = (const float*)d_in[0];
    const float* trans  = (const float*)d_in[1];
    const int*   tags   = (const int*)d_in[2];
    const int*   lens   = (const int*)d_in[3];

    u32*   wmat  = (u32*)d_ws;                                   // 16 MB
    float* woff  = (float*)((char*)d_ws + 16u*1024u*1024u);      // 32 KB
    float* gpart = woff + 8192;                                  // 32 KB

    crf_chunk  <<<4096, 128, 0, stream>>>(logits, trans, tags, lens,
                                          wmat, woff, gpart, (float*)d_out);
    crf_combine<<< 256, 256, 0, stream>>>(logits, wmat, woff, gpart,
                                          (float*)d_out);
}